// Round 5
// baseline (324.454 us; speedup 1.0000x reference)
//
#include <hip/hip_runtime.h>
#include <cfloat>

constexpr int NB   = 65;     // N_BINS (= OUTPUT_SIZE)
constexpr int LROW = 8192;   // L
constexpr int NT   = 512;    // threads per block
constexpr int EPT  = LROW / NT; // 16 elements per thread

// Bijective LDS swizzle, quad(16B)-preserving: word w -> w ^ (((w>>5)&31)<<2).
// Spreads blocked float4 accesses (lane stride 64B) and stride-1 pass patterns
// across all 32 banks. Invertible (bits 2..6 ^= bits 5..9, triangular).
__device__ __forceinline__ int SWW(int w) { return w ^ (((w >> 5) & 31) << 2); }
__device__ __forceinline__ int SWQ(int q) { return q ^ ((q >> 3) & 31); }

__global__ __launch_bounds__(NT) void mtf_kernel(const float* __restrict__ x,
                                                 float* __restrict__ out) {
    __shared__ __align__(16) float vals[LROW];   // 32 KB (swizzled storage)
    __shared__ unsigned int hist[NB * NB];       // 16.9 KB
    __shared__ float edges[NB];
    __shared__ int firstbin[NT];
    __shared__ int s_first, s_last;

    const int row = blockIdx.x;          // n*C + c
    const int tid = threadIdx.x;
    const float* __restrict__ xr = x + (size_t)row * LROW;

    if (tid == 0) { s_first = LROW; s_last = -1; }
    for (int i = tid; i < NB * NB; i += NT) hist[i] = 0u;

    // ---- load row into LDS (swizzled), find first/last nonzero ----
    int lfirst = LROW, llast = -1;
    for (int i = tid; i < LROW; i += NT) {
        float v = xr[i];
        vals[SWW(i)] = v;
        if (v != 0.0f) { lfirst = min(lfirst, i); llast = max(llast, i); }
    }
    __syncthreads();
    if (llast >= 0) { atomicMin(&s_first, lfirst); atomicMax(&s_last, llast); }
    __syncthreads();
    const int first = s_first;
    const int last  = s_last;
    const int m     = (last >= 0) ? (last - first + 1) : 0;   // mask.sum()

    // ---- mask: out-of-range -> FLT_MAX (reference's `big`) ----
    for (int i = tid; i < LROW; i += NT) {
        if (m == 0 || i < first || i > last) vals[SWW(i)] = FLT_MAX;
    }
    __syncthreads();

    // ---- register-blocked bitonic sort (ascending) ----
    // Thread t owns global indices [16t, 16t+16). Passes with j<=8 run in
    // registers; direction rule everywhere: ascending iff (global_i & k)==0.
    float r[16];
    float4* v4 = (float4*)vals;
    const int qbase = tid * 4;

    #pragma unroll
    for (int q = 0; q < 4; ++q) {
        float4 t4 = v4[SWQ(qbase + q)];
        r[4*q+0] = t4.x; r[4*q+1] = t4.y; r[4*q+2] = t4.z; r[4*q+3] = t4.w;
    }

    // stages k=2,4,8: direction from local index (block base is multiple of 16)
    #pragma unroll
    for (int k = 2; k <= 8; k <<= 1) {
        #pragma unroll
        for (int j = k >> 1; j > 0; j >>= 1) {
            #pragma unroll
            for (int l = 0; l < 16; ++l) if ((l & j) == 0) {
                bool up = ((l & k) == 0);
                float a = r[l], b = r[l | j];
                if ((a > b) == up) { r[l] = b; r[l | j] = a; }
            }
        }
    }
    // stage k=16: direction uniform per thread (bit4 of base = tid&1)
    {
        bool up = ((tid & 1) == 0);
        #pragma unroll
        for (int j = 8; j > 0; j >>= 1) {
            #pragma unroll
            for (int l = 0; l < 16; ++l) if ((l & j) == 0) {
                float a = r[l], b = r[l | j];
                if ((a > b) == up) { r[l] = b; r[l | j] = a; }
            }
        }
    }

    // stages k=32..8192: LDS passes for j>=16, register passes for j<=8
    for (int k = 32; k <= LROW; k <<= 1) {
        #pragma unroll
        for (int q = 0; q < 4; ++q)
            v4[SWQ(qbase + q)] = make_float4(r[4*q], r[4*q+1], r[4*q+2], r[4*q+3]);
        __syncthreads();

        for (int j = k >> 1; j >= 16; j >>= 1) {
            #pragma unroll
            for (int qq = 0; qq < (LROW / 2) / NT; ++qq) {
                int p   = tid + qq * NT;
                int i   = ((p & ~(j - 1)) << 1) | (p & (j - 1));
                int ixj = i | j;
                int wi  = SWW(i), wx = SWW(ixj);
                float a = vals[wi], b = vals[wx];
                bool up = ((i & k) == 0);
                if ((a > b) == up) { vals[wi] = b; vals[wx] = a; }
            }
            __syncthreads();
        }

        #pragma unroll
        for (int q = 0; q < 4; ++q) {
            float4 t4 = v4[SWQ(qbase + q)];
            r[4*q+0] = t4.x; r[4*q+1] = t4.y; r[4*q+2] = t4.z; r[4*q+3] = t4.w;
        }
        bool up = (((tid * 16) & k) == 0);   // wave... thread-uniform for k>=32
        #pragma unroll
        for (int j = 8; j > 0; j >>= 1) {
            #pragma unroll
            for (int l = 0; l < 16; ++l) if ((l & j) == 0) {
                float a = r[l], b = r[l | j];
                if ((a > b) == up) { r[l] = b; r[l | j] = a; }
            }
        }
        // next iteration stores own block; no cross-thread access until after
        // its barrier, so no extra sync needed here
    }
    #pragma unroll
    for (int q = 0; q < 4; ++q)
        v4[SWQ(qbase + q)] = make_float4(r[4*q], r[4*q+1], r[4*q+2], r[4*q+3]);
    __syncthreads();

    // ---- 65 quantile edges (match JAX f32 op-for-op) ----
    // jnp.linspace(0,1,66): delta = fl(1/65); qlev[k] = fl(k*delta).
    // pos = qlev*(m-1); frac = pos-floor(pos); q = vlo + frac*(vhi-vlo)
    // -- separate round-to-nearest f32 ops, no FMA contraction.
    if (tid < NB) {
        float e = 0.0f;
        if (m > 0) {
            const float delta = __fdiv_rn(1.0f, 65.0f);
            float qv   = __fmul_rn((float)tid, delta);
            float pos  = __fmul_rn(qv, (float)(m - 1));
            float flo  = floorf(pos);
            float frac = __fsub_rn(pos, flo);
            int lo = (int)flo;
            int hi = (int)ceilf(pos);
            float vlo = vals[SWW(lo)];
            float vhi = vals[SWW(hi)];
            e = __fadd_rn(vlo, __fmul_rn(frac, __fsub_rn(vhi, vlo)));
        }
        edges[tid] = e;
    }
    __syncthreads();

    // ---- bin all 8192 elements: searchsorted(edges, v, 'right'), clip 64 ----
    int bl[EPT];
    const int base = tid * EPT;
    #pragma unroll
    for (int u = 0; u < EPT; ++u) {
        float v = xr[base + u];
        int lo = 0, hi = NB;
        #pragma unroll
        for (int it = 0; it < 7; ++it) {      // ceil(log2(66)) = 7
            if (lo < hi) {
                int mid = (lo + hi) >> 1;
                if (v < edges[mid]) hi = mid; else lo = mid + 1;
            }
        }
        bl[u] = min(lo, NB - 1);
    }

    // ---- transition histogram over 8191 consecutive pairs ----
    firstbin[tid] = bl[0];
    #pragma unroll
    for (int u = 0; u + 1 < EPT; ++u)
        atomicAdd(&hist[bl[u] * NB + bl[u + 1]], 1u);
    __syncthreads();
    if (tid + 1 < NT)
        atomicAdd(&hist[bl[EPT - 1] * NB + firstbin[tid + 1]], 1u);
    __syncthreads();

    // ---- write out: hist / (L-1) ----
    float* __restrict__ orow = out + (size_t)row * (NB * NB);
    for (int i = tid; i < NB * NB; i += NT)
        orow[i] = __fdiv_rn((float)hist[i], (float)(LROW - 1));
}

extern "C" void kernel_launch(void* const* d_in, const int* in_sizes, int n_in,
                              void* d_out, int out_size, void* d_ws, size_t ws_size,
                              hipStream_t stream) {
    const float* x = (const float*)d_in[0];
    float* out = (float*)d_out;
    const int rows = in_sizes[0] / LROW;   // N*C = 2048
    mtf_kernel<<<rows, NT, 0, stream>>>(x, out);
}

// Round 6
// 269.873 us; speedup vs baseline: 1.2022x; 1.2022x over previous
//
#include <hip/hip_runtime.h>
#include <cfloat>

constexpr int NB   = 65;      // N_BINS (= OUTPUT_SIZE)
constexpr int LROW = 8192;    // L
constexpr int NT   = 512;     // threads per block
constexpr int EPT  = 16;      // elements per thread
constexpr int NBUK = 2048;    // value buckets for multiselect

// Monotone bucket map: v in (-inf, +inf) -> [0, NBUK).  Equal v -> equal bucket.
// Range [-6, 6] chosen so real data never clamps (normals); clamping is still
// correct (monotone) for arbitrary input, just degrades selection speed.
__device__ __forceinline__ int bucket_of(float v) {
    float t = (v + 6.0f) * (float(NBUK) / 12.0f);
    t = fminf(fmaxf(t, 0.0f), float(NBUK - 1));
    return (int)t;
}

__global__ __launch_bounds__(NT) void mtf_kernel(const float* __restrict__ x,
                                                 float* __restrict__ out) {
    __shared__ __align__(16) float vals[LROW];     // 32 KB: bucket-grouped values; later aliased as transition hist
    __shared__ unsigned int arr[NBUK];             // 8 KB: counts -> excl prefix -> incl ends
    __shared__ float edges[NB];
    __shared__ int firstbin[NT];
    __shared__ unsigned int wsum[8];
    __shared__ int s_first, s_last;

    const int row  = blockIdx.x;          // n*C + c
    const int tid  = threadIdx.x;
    const int lane = tid & 63;
    const int wid  = tid >> 6;
    const float* __restrict__ xr = x + (size_t)row * LROW;

    if (tid == 0) { s_first = LROW; s_last = -1; }
    #pragma unroll
    for (int q = 0; q < NBUK / NT; ++q) arr[tid + q * NT] = 0u;

    // ---- load 16 contiguous elements into registers ----
    float v[EPT];
    const int base = tid * EPT;
    #pragma unroll
    for (int q = 0; q < 4; ++q) {
        float4 t = *reinterpret_cast<const float4*>(xr + base + q * 4);
        v[q*4+0] = t.x; v[q*4+1] = t.y; v[q*4+2] = t.z; v[q*4+3] = t.w;
    }

    // ---- first/last nonzero: per-thread, wave-reduce, one atomic per wave ----
    int lfirst = LROW, llast = -1;
    #pragma unroll
    for (int u = 0; u < EPT; ++u)
        if (v[u] != 0.0f) { lfirst = min(lfirst, base + u); llast = max(llast, base + u); }
    #pragma unroll
    for (int d = 32; d > 0; d >>= 1) {
        lfirst = min(lfirst, __shfl_xor(lfirst, d));
        llast  = max(llast,  __shfl_xor(llast,  d));
    }
    __syncthreads();                      // init (s_first/arr) visible before atomics
    if (lane == 0) {
        if (llast >= 0) { atomicMin(&s_first, lfirst); atomicMax(&s_last, llast); }
    }
    __syncthreads();
    const int first = s_first;
    const int last  = s_last;
    const int m     = (last >= 0) ? (last - first + 1) : 0;   // mask.sum()

    // ---- count in-range elements into buckets (masked elements never placed;
    //      ranks only reach m-1, so the FLT_MAX tail is unnecessary) ----
    #pragma unroll
    for (int u = 0; u < EPT; ++u) {
        int idx = base + u;
        if (m > 0 && idx >= first && idx <= last)
            atomicAdd(&arr[bucket_of(v[u])], 1u);
    }
    __syncthreads();

    // ---- in-place exclusive scan of arr[0..NBUK) (4 counters per thread) ----
    {
        uint4 c = *reinterpret_cast<uint4*>(&arr[tid * 4]);
        unsigned own = c.x + c.y + c.z + c.w;
        unsigned inc = own;                       // wave inclusive scan of thread sums
        #pragma unroll
        for (int d = 1; d < 64; d <<= 1) {
            unsigned n = __shfl_up(inc, d);
            if (lane >= d) inc += n;
        }
        if (lane == 63) wsum[wid] = inc;
        __syncthreads();
        if (tid == 0) {
            unsigned s = 0;
            #pragma unroll
            for (int w = 0; w < 8; ++w) { unsigned t = wsum[w]; wsum[w] = s; s += t; }
        }
        __syncthreads();
        unsigned b0 = wsum[wid] + (inc - own);    // exclusive prefix of this thread's chunk
        arr[tid*4+0] = b0;
        arr[tid*4+1] = b0 + c.x;
        arr[tid*4+2] = b0 + c.x + c.y;
        arr[tid*4+3] = b0 + c.x + c.y + c.z;
    }
    __syncthreads();

    // ---- scatter: atomic-consume prefix -> arr becomes inclusive bucket ends ----
    #pragma unroll
    for (int u = 0; u < EPT; ++u) {
        int idx = base + u;
        if (m > 0 && idx >= first && idx <= last) {
            unsigned slot = atomicAdd(&arr[bucket_of(v[u])], 1u);
            vals[slot] = v[u];
        }
    }
    __syncthreads();

    // ---- 65 quantile edges via rank selection (match JAX f32 op-for-op) ----
    // jnp.linspace(0,1,66): delta = fl(1/65); qlev[k] = fl(k*delta).
    // pos = qlev*(m-1); frac = pos-floor(pos); q = vlo + frac*(vhi-vlo)
    // -- separate round-to-nearest f32 ops, no FMA contraction.
    if (tid < NB) {
        float e = 0.0f;
        if (m > 0) {
            const float delta = __fdiv_rn(1.0f, 65.0f);
            float qv   = __fmul_rn((float)tid, delta);
            float pos  = __fmul_rn(qv, (float)(m - 1));
            float flo  = floorf(pos);
            float frac = __fsub_rn(pos, flo);
            int lo = (int)flo;
            int hi = (int)ceilf(pos);

            float vsel[2]; int rr[2] = { lo, hi };
            #pragma unroll
            for (int s = 0; s < 2; ++s) {
                int r = rr[s];
                if (s == 1 && hi == lo) { vsel[1] = vsel[0]; break; }
                // bucket containing rank r: smallest b with ends[b] > r
                int loB = 0, hiB = NBUK - 1;
                while (loB < hiB) {
                    int mid = (loB + hiB) >> 1;
                    if (arr[mid] > (unsigned)r) hiB = mid; else loB = mid + 1;
                }
                int st = (loB == 0) ? 0 : (int)arr[loB - 1];
                int en = (int)arr[loB];
                int rl = r - st;
                // selection by counting (tie-correct, order-independent)
                float ans = vals[st];
                for (int i = st; i < en; ++i) {
                    float vi = vals[i];
                    int cl = 0, ce = 0;
                    for (int j = st; j < en; ++j) {
                        float vj = vals[j];
                        cl += (vj < vi);
                        ce += (vj == vi);
                    }
                    if (cl <= rl && rl < cl + ce) { ans = vi; break; }
                }
                vsel[s] = ans;
            }
            e = __fadd_rn(vsel[0], __fmul_rn(frac, __fsub_rn(vsel[1], vsel[0])));
        }
        edges[tid] = e;
    }
    __syncthreads();

    // ---- vals region is dead; alias it as the transition histogram ----
    unsigned int* thist = reinterpret_cast<unsigned int*>(vals);
    for (int i = tid; i < NB * NB; i += NT) thist[i] = 0u;
    __syncthreads();

    // ---- bin all 8192 original elements: searchsorted(edges, v, 'right') ----
    int bl[EPT];
    #pragma unroll
    for (int u = 0; u < EPT; ++u) {
        float vv = v[u];
        int lo = 0, hi = NB;
        #pragma unroll
        for (int it = 0; it < 7; ++it) {          // ceil(log2(66)) = 7
            if (lo < hi) {
                int mid = (lo + hi) >> 1;
                if (vv < edges[mid]) hi = mid; else lo = mid + 1;
            }
        }
        bl[u] = min(lo, NB - 1);
    }

    // ---- transition histogram over 8191 consecutive pairs ----
    firstbin[tid] = bl[0];
    __syncthreads();
    #pragma unroll
    for (int u = 0; u + 1 < EPT; ++u)
        atomicAdd(&thist[bl[u] * NB + bl[u + 1]], 1u);
    if (tid + 1 < NT)
        atomicAdd(&thist[bl[EPT - 1] * NB + firstbin[tid + 1]], 1u);
    __syncthreads();

    // ---- write out: hist / (L-1) ----
    float* __restrict__ orow = out + (size_t)row * (NB * NB);
    for (int i = tid; i < NB * NB; i += NT)
        orow[i] = __fdiv_rn((float)thist[i], (float)(LROW - 1));
}

extern "C" void kernel_launch(void* const* d_in, const int* in_sizes, int n_in,
                              void* d_out, int out_size, void* d_ws, size_t ws_size,
                              hipStream_t stream) {
    const float* x = (const float*)d_in[0];
    float* out = (float*)d_out;
    const int rows = in_sizes[0] / LROW;   // N*C = 2048
    mtf_kernel<<<rows, NT, 0, stream>>>(x, out);
}

// Round 7
// 170.141 us; speedup vs baseline: 1.9070x; 1.5862x over previous
//
#include <hip/hip_runtime.h>
#include <cfloat>

constexpr int NB   = 65;      // N_BINS (= OUTPUT_SIZE)
constexpr int LROW = 8192;    // L
constexpr int NT   = 512;     // threads per block
constexpr int EPT  = 16;      // elements per thread
constexpr int NBUK = 1024;    // value buckets for multiselect

// Monotone bucket map: v -> [0, NBUK). Equal v -> equal bucket. Clamping is
// monotone, so correctness never depends on the [-6,6] range assumption.
__device__ __forceinline__ int bucket_of(float v) {
    float t = (v + 6.0f) * (float(NBUK) / 12.0f);
    t = fminf(fmaxf(t, 0.0f), float(NBUK - 1));
    return (int)t;
}

__global__ __launch_bounds__(NT, 8) void mtf_kernel(const float* __restrict__ x,
                                                    float* __restrict__ out) {
    __shared__ __align__(16) float vals[LROW];      // 32 KB: bucket-grouped; later aliased as transition hist
    __shared__ __align__(16) unsigned int arr[NBUK];// 4 KB: counts -> excl prefix -> incl ends
    __shared__ unsigned int tops[64];               // arr[16i+15]: level-1 for 64-ary search
    __shared__ float edges[NB];
    __shared__ unsigned int wsum[8];
    __shared__ int wfirst[8];                       // per-wave lane-0 first bin
    __shared__ int s_first, s_last;

    const int row  = blockIdx.x;          // n*C + c
    const int tid  = threadIdx.x;
    const int lane = tid & 63;
    const int wid  = tid >> 6;
    const float* __restrict__ xr = x + (size_t)row * LROW;

    if (tid == 0) { s_first = LROW; s_last = -1; }
    #pragma unroll
    for (int q = 0; q < NBUK / NT; ++q) arr[tid + q * NT] = 0u;

    // ---- load 16 contiguous elements into registers ----
    float v[EPT];
    const int base = tid * EPT;
    #pragma unroll
    for (int q = 0; q < 4; ++q) {
        float4 t = *reinterpret_cast<const float4*>(xr + base + q * 4);
        v[q*4+0] = t.x; v[q*4+1] = t.y; v[q*4+2] = t.z; v[q*4+3] = t.w;
    }

    // ---- first/last nonzero: thread -> wave-reduce -> one atomic per wave ----
    int lfirst = LROW, llast = -1;
    #pragma unroll
    for (int u = 0; u < EPT; ++u)
        if (v[u] != 0.0f) { lfirst = min(lfirst, base + u); llast = max(llast, base + u); }
    #pragma unroll
    for (int d = 32; d > 0; d >>= 1) {
        lfirst = min(lfirst, __shfl_xor(lfirst, d));
        llast  = max(llast,  __shfl_xor(llast,  d));
    }
    __syncthreads();                      // init visible before atomics
    if (lane == 0 && llast >= 0) { atomicMin(&s_first, lfirst); atomicMax(&s_last, llast); }
    __syncthreads();
    const int first = s_first, last = s_last;
    const int m = (last >= 0) ? (last - first + 1) : 0;   // mask.sum()

    // ---- bucket counts (masked elements never placed; ranks only reach m-1) ----
    #pragma unroll
    for (int u = 0; u < EPT; ++u) {
        int idx = base + u;
        if (m > 0 && idx >= first && idx <= last)
            atomicAdd(&arr[bucket_of(v[u])], 1u);
    }
    __syncthreads();

    // ---- in-place exclusive scan of arr[0..NBUK) (2 counters/thread) ----
    {
        uint2 c = *reinterpret_cast<uint2*>(&arr[tid * 2]);
        unsigned own = c.x + c.y;
        unsigned inc = own;
        #pragma unroll
        for (int d = 1; d < 64; d <<= 1) {
            unsigned n = __shfl_up(inc, d);
            if (lane >= d) inc += n;
        }
        if (lane == 63) wsum[wid] = inc;
        __syncthreads();
        if (wid == 0) {                   // wave-parallel 8-element exclusive scan
            unsigned t0 = (lane < 8) ? wsum[lane] : 0u;
            unsigned sc = t0;
            #pragma unroll
            for (int d = 1; d < 8; d <<= 1) {
                unsigned n = __shfl_up(sc, d);
                if (lane >= d) sc += n;
            }
            if (lane < 8) wsum[lane] = sc - t0;
        }
        __syncthreads();
        unsigned b0 = wsum[wid] + (inc - own);
        arr[tid*2+0] = b0;
        arr[tid*2+1] = b0 + c.x;
    }
    __syncthreads();

    // ---- scatter: atomic-consume prefix -> arr becomes inclusive bucket ends ----
    #pragma unroll
    for (int u = 0; u < EPT; ++u) {
        int idx = base + u;
        if (m > 0 && idx >= first && idx <= last) {
            unsigned slot = atomicAdd(&arr[bucket_of(v[u])], 1u);
            vals[slot] = v[u];
        }
    }
    __syncthreads();
    if (tid < 64) tops[tid] = arr[tid * 16 + 15];   // level-1 search table
    __syncthreads();

    // ---- edges: ONE WAVE PER EDGE (wave-parallel selection) ----
    // jnp.linspace(0,1,66): delta = fl(1/65); qlev[k] = fl(k*delta).
    // pos = qlev*(m-1); frac = pos-floor(pos); q = vlo + frac*(vhi-vlo)
    // -- separate round-to-nearest f32 ops, no FMA contraction.
    for (int k = wid; k < NB; k += 8) {
        if (m == 0) { if (lane == 0) edges[k] = 0.0f; continue; }
        const float delta = __fdiv_rn(1.0f, 65.0f);
        float qv   = __fmul_rn((float)k, delta);
        float pos  = __fmul_rn(qv, (float)(m - 1));
        float flo  = floorf(pos);
        float frac = __fsub_rn(pos, flo);
        int lo = (int)flo;
        int hi = (int)ceilf(pos);

        // two-level 64-ary search: smallest b with arr[b] > r (arr = incl ends)
        int bL, bH;
        {
            unsigned long long b1 = __ballot((int)tops[lane] > lo);
            int seg = __ffsll(b1) - 1;                      // tops[63]=m>lo: nonzero
            unsigned long long b2 = __ballot(lane < 16 && (int)arr[seg*16 + lane] > lo);
            bL = seg * 16 + __ffsll(b2) - 1;
        }
        if (hi == lo) bH = bL;
        else {
            unsigned long long b1 = __ballot((int)tops[lane] > hi);
            int seg = __ffsll(b1) - 1;
            unsigned long long b2 = __ballot(lane < 16 && (int)arr[seg*16 + lane] > hi);
            bH = seg * 16 + __ffsll(b2) - 1;
        }

        int stL = bL ? (int)arr[bL - 1] : 0;
        int enL = (int)arr[bL];
        int rlo = lo - stL, rhi = hi - stL;
        bool sameB = (bH == bL);
        float vlo = 0.0f, vhi = 0.0f;
        bool fL = false, fH = !sameB;
        // counting selection: lane = candidate; inner loop is LDS broadcast
        for (int b0 = stL; b0 < enL; b0 += 64) {
            int i = b0 + lane;
            bool act = i < enL;
            float vi = act ? vals[i] : 0.0f;
            int cl = 0, ce = 0;
            for (int j = stL; j < enL; ++j) {
                float vj = vals[j];
                cl += (vj < vi);
                ce += (vj == vi);
            }
            if (!fL) {
                unsigned long long mk = __ballot(act && cl <= rlo && rlo < cl + ce);
                if (mk) { vlo = __shfl(vi, __ffsll(mk) - 1); fL = true; }
            }
            if (!fH) {
                unsigned long long mk = __ballot(act && cl <= rhi && rhi < cl + ce);
                if (mk) { vhi = __shfl(vi, __ffsll(mk) - 1); fH = true; }
            }
            if (fL && fH) break;
        }
        if (!sameB) {
            // hi's in-bucket rank is 0 by prefix continuity -> bucket minimum
            int stH = (int)arr[bH - 1], enH = (int)arr[bH];   // bH > bL >= 0
            float mn = FLT_MAX;
            for (int i = stH + lane; i < enH; i += 64) mn = fminf(mn, vals[i]);
            #pragma unroll
            for (int d = 32; d > 0; d >>= 1) mn = fminf(mn, __shfl_xor(mn, d));
            vhi = mn;
        }
        if (lane == 0)
            edges[k] = __fadd_rn(vlo, __fmul_rn(frac, __fsub_rn(vhi, vlo)));
    }
    __syncthreads();

    // ---- vals dead: alias as transition histogram; zero overlaps binning ----
    unsigned int* thist = reinterpret_cast<unsigned int*>(vals);
    for (int i = tid; i < NB * NB; i += NT) thist[i] = 0u;

    int bl[EPT];
    #pragma unroll
    for (int u = 0; u < EPT; ++u) {
        float vv = v[u];
        int lo2 = 0, hi2 = NB;
        #pragma unroll
        for (int it = 0; it < 7; ++it) {          // ceil(log2(66)) = 7
            if (lo2 < hi2) {
                int mid = (lo2 + hi2) >> 1;
                if (vv < edges[mid]) hi2 = mid; else lo2 = mid + 1;
            }
        }
        bl[u] = min(lo2, NB - 1);
    }
    if (lane == 0) wfirst[wid] = bl[0];
    __syncthreads();

    // ---- transition histogram over 8191 consecutive pairs ----
    int nxt0 = __shfl_down(bl[0], 1);             // next thread's first bin
    if (lane == 63 && wid < 7) nxt0 = wfirst[wid + 1];
    #pragma unroll
    for (int u = 0; u + 1 < EPT; ++u)
        atomicAdd(&thist[bl[u] * NB + bl[u + 1]], 1u);
    if (tid + 1 < NT)
        atomicAdd(&thist[bl[EPT - 1] * NB + nxt0], 1u);
    __syncthreads();

    // ---- write out: hist / (L-1) ----
    float* __restrict__ orow = out + (size_t)row * (NB * NB);
    for (int i = tid; i < NB * NB; i += NT)
        orow[i] = __fdiv_rn((float)thist[i], (float)(LROW - 1));
}

extern "C" void kernel_launch(void* const* d_in, const int* in_sizes, int n_in,
                              void* d_out, int out_size, void* d_ws, size_t ws_size,
                              hipStream_t stream) {
    const float* x = (const float*)d_in[0];
    float* out = (float*)d_out;
    const int rows = in_sizes[0] / LROW;   // N*C = 2048
    mtf_kernel<<<rows, NT, 0, stream>>>(x, out);
}